// Round 1
// baseline (284.396 us; speedup 1.0000x reference)
//
#include <hip/hip_runtime.h>

// Problem constants (from reference): S=4096, H=3, E=512, G=3334, F=1
constexpr int S = 4096;
constexpr int H = 3;
constexpr int E = 512;
constexpr int G = 3334;
constexpr float RES = 0.03f;  // INTEGRAL_RESOLUTION

// output = sum_{masked events}(base_h + w_h*x) - RES * sum_{grid}(exp(base_h + w_h*y))
__global__ __launch_bounds__(256) void logic_model_kernel(
    const float* __restrict__ ev,     // [S*H*E] event_features (F=1)
    const int*   __restrict__ mask,   // [S*H*E] event_mask (0/1)
    const float* __restrict__ gr,     // [S*H*G] grid_features (F=1)
    const float* __restrict__ w,      // [H] weights (F=1)
    const float* __restrict__ bases,  // [H]
    const float* __restrict__ eff,    // [H] effects (F=1)
    float* __restrict__ out)
{
    // Per-head constants in registers; H==3 so select with cndmask chains.
    const float b0 = bases[0], b1 = bases[1], b2 = bases[2];
    const float w0 = w[0] * eff[0], w1 = w[1] * eff[1], w2 = w[2] * eff[2];

    const int tid = blockIdx.x * blockDim.x + threadIdx.x;
    const int nthreads = gridDim.x * blockDim.x;

    // ---- Part 1: masked event log-sum (float4 + int4, 128 f4 per (s,h) row) ----
    float acc_ev = 0.f;
    const int nf4 = S * H * E / 4;            // 1,572,864
    const float4* ev4 = (const float4*)ev;
    const int4*   m4  = (const int4*)mask;
    for (int i = tid; i < nf4; i += nthreads) {
        float4 x = ev4[i];
        int4   m = m4[i];
        int row = i >> 7;                      // E/4 = 128 float4 per row
        int h = row % 3;
        float bb = (h == 0) ? b0 : ((h == 1) ? b1 : b2);
        float ww = (h == 0) ? w0 : ((h == 1) ? w1 : w2);
        if (m.x) acc_ev += bb + ww * x.x;
        if (m.y) acc_ev += bb + ww * x.y;
        if (m.z) acc_ev += bb + ww * x.z;
        if (m.w) acc_ev += bb + ww * x.w;
    }

    // ---- Part 2: grid exp-sum (float2; G=3334 -> rows only 8B aligned) ----
    float acc_gr = 0.f;
    const int nf2 = S * H * G / 2;            // 20,484,096
    const float2* gr2 = (const float2*)gr;
    for (int i = tid; i < nf2; i += nthreads) {
        float2 y = gr2[i];
        int row = i / 1667;                    // G/2 = 1667 float2 per row
        int h = row % 3;
        float bb = (h == 0) ? b0 : ((h == 1) ? b1 : b2);
        float ww = (h == 0) ? w0 : ((h == 1) ? w1 : w2);
        acc_gr += __expf(bb + ww * y.x) + __expf(bb + ww * y.y);
    }

    float v = acc_ev - RES * acc_gr;

    // ---- Block reduction: wave64 shuffle -> LDS -> one atomic per block ----
    #pragma unroll
    for (int off = 32; off > 0; off >>= 1)
        v += __shfl_down(v, off, 64);

    __shared__ float sdata[4];                 // 256 threads / 64 = 4 waves
    const int wave = threadIdx.x >> 6;
    const int lane = threadIdx.x & 63;
    if (lane == 0) sdata[wave] = v;
    __syncthreads();
    if (threadIdx.x == 0) {
        float t = sdata[0] + sdata[1] + sdata[2] + sdata[3];
        atomicAdd(out, t);
    }
}

extern "C" void kernel_launch(void* const* d_in, const int* in_sizes, int n_in,
                              void* d_out, int out_size, void* d_ws, size_t ws_size,
                              hipStream_t stream) {
    const float* ev    = (const float*)d_in[0];  // event_features [S,H,E,1]
    const int*   mask  = (const int*)  d_in[1];  // event_mask     [S,H,E]
    const float* gr    = (const float*)d_in[2];  // grid_features  [S,H,G,1]
    const float* w     = (const float*)d_in[3];  // weights        [H,1]
    const float* bases = (const float*)d_in[4];  // bases          [H]
    const float* eff   = (const float*)d_in[5];  // effects        [H,1]
    float* out = (float*)d_out;

    // d_out is poisoned 0xAA before every timed launch — zero it (capture-legal).
    hipMemsetAsync(out, 0, sizeof(float), stream);

    logic_model_kernel<<<2048, 256, 0, stream>>>(ev, mask, gr, w, bases, eff, out);
}

// Round 2
// 276.159 us; speedup vs baseline: 1.0298x; 1.0298x over previous
//
#include <hip/hip_runtime.h>

// Problem constants (from reference): S=4096, H=3, E=512, G=3334, F=1
constexpr int S = 4096;
constexpr int H = 3;
constexpr int E = 512;
constexpr int G = 3334;
constexpr float RES = 0.03f;  // INTEGRAL_RESOLUTION

// Per-element head coefficients: j is the flat index into [S,H,G]; h=(j/G)%3.
// Compiler lowers /G and %3 to magic-mul sequences (no HW int div on gfx950).
__device__ __forceinline__ float exp_term(int j, float y,
                                          float b0, float b1, float b2,
                                          float w0, float w1, float w2) {
    int h = (j / G) % 3;
    float bb = (h == 0) ? b0 : ((h == 1) ? b1 : b2);
    float ww = (h == 0) ? w0 : ((h == 1) ? w1 : w2);
    return __expf(bb + ww * y);
}

__global__ __launch_bounds__(256) void logic_model_kernel(
    const float* __restrict__ ev,     // [S*H*E] event_features (F=1)
    const int*   __restrict__ mask,   // [S*H*E] event_mask (0/1)
    const float* __restrict__ gr,     // [S*H*G] grid_features (F=1)
    const float* __restrict__ w,      // [H] weights (F=1)
    const float* __restrict__ bases,  // [H]
    const float* __restrict__ eff,    // [H] effects (F=1)
    float* __restrict__ out)
{
    const float b0 = bases[0], b1 = bases[1], b2 = bases[2];
    const float w0 = w[0] * eff[0], w1 = w[1] * eff[1], w2 = w[2] * eff[2];

    const int tid = blockIdx.x * blockDim.x + threadIdx.x;
    const int nthreads = gridDim.x * blockDim.x;   // 2048*256 = 524288

    // ---- Part 1: masked event log-sum. nf4 = 1,572,864 = exactly 3*nthreads.
    float acc_ev = 0.f;
    const int nf4 = S * H * E / 4;
    const float4* ev4 = (const float4*)ev;
    const int4*   m4  = (const int4*)mask;
    {
        int i0 = tid, i1 = tid + nthreads, i2 = tid + 2 * nthreads;
        float4 x0 = ev4[i0], x1 = ev4[i1], x2 = ev4[i2];
        int4   a0 = m4[i0],  a1 = m4[i1],  a2 = m4[i2];
        (void)nf4;
        #pragma unroll
        for (int k = 0; k < 3; ++k) {
            int i = (k == 0) ? i0 : ((k == 1) ? i1 : i2);
            float4 x = (k == 0) ? x0 : ((k == 1) ? x1 : x2);
            int4   m = (k == 0) ? a0 : ((k == 1) ? a1 : a2);
            int row = i >> 7;                  // E/4 = 128 float4 per (s,h) row
            int h = row % 3;
            float bb = (h == 0) ? b0 : ((h == 1) ? b1 : b2);
            float ww = (h == 0) ? w0 : ((h == 1) ? w1 : w2);
            if (m.x) acc_ev += bb + ww * x.x;
            if (m.y) acc_ev += bb + ww * x.y;
            if (m.z) acc_ev += bb + ww * x.z;
            if (m.w) acc_ev += bb + ww * x.w;
        }
    }

    // ---- Part 2: grid exp-sum, flat float4 loads (16B/lane), unroll x4 so
    // each wave has 4 independent loads (64B/lane) in flight.
    float acc_gr = 0.f;
    const int nf4g = S * H * G / 4;            // 10,242,048
    const float4* gr4 = (const float4*)gr;
    int i = tid;
    for (; i + 3 * nthreads < nf4g; i += 4 * nthreads) {
        float4 y0 = gr4[i];
        float4 y1 = gr4[i + nthreads];
        float4 y2 = gr4[i + 2 * nthreads];
        float4 y3 = gr4[i + 3 * nthreads];
        int j0 = 4 * i;
        int j1 = 4 * (i + nthreads);
        int j2 = 4 * (i + 2 * nthreads);
        int j3 = 4 * (i + 3 * nthreads);
        acc_gr += exp_term(j0 + 0, y0.x, b0, b1, b2, w0, w1, w2)
                + exp_term(j0 + 1, y0.y, b0, b1, b2, w0, w1, w2)
                + exp_term(j0 + 2, y0.z, b0, b1, b2, w0, w1, w2)
                + exp_term(j0 + 3, y0.w, b0, b1, b2, w0, w1, w2);
        acc_gr += exp_term(j1 + 0, y1.x, b0, b1, b2, w0, w1, w2)
                + exp_term(j1 + 1, y1.y, b0, b1, b2, w0, w1, w2)
                + exp_term(j1 + 2, y1.z, b0, b1, b2, w0, w1, w2)
                + exp_term(j1 + 3, y1.w, b0, b1, b2, w0, w1, w2);
        acc_gr += exp_term(j2 + 0, y2.x, b0, b1, b2, w0, w1, w2)
                + exp_term(j2 + 1, y2.y, b0, b1, b2, w0, w1, w2)
                + exp_term(j2 + 2, y2.z, b0, b1, b2, w0, w1, w2)
                + exp_term(j2 + 3, y2.w, b0, b1, b2, w0, w1, w2);
        acc_gr += exp_term(j3 + 0, y3.x, b0, b1, b2, w0, w1, w2)
                + exp_term(j3 + 1, y3.y, b0, b1, b2, w0, w1, w2)
                + exp_term(j3 + 2, y3.z, b0, b1, b2, w0, w1, w2)
                + exp_term(j3 + 3, y3.w, b0, b1, b2, w0, w1, w2);
    }
    for (; i < nf4g; i += nthreads) {
        float4 y = gr4[i];
        int j = 4 * i;
        acc_gr += exp_term(j + 0, y.x, b0, b1, b2, w0, w1, w2)
                + exp_term(j + 1, y.y, b0, b1, b2, w0, w1, w2)
                + exp_term(j + 2, y.z, b0, b1, b2, w0, w1, w2)
                + exp_term(j + 3, y.w, b0, b1, b2, w0, w1, w2);
    }

    float v = acc_ev - RES * acc_gr;

    // ---- Block reduction: wave64 shuffle -> LDS -> one atomic per block ----
    #pragma unroll
    for (int off = 32; off > 0; off >>= 1)
        v += __shfl_down(v, off, 64);

    __shared__ float sdata[4];                 // 256 threads / 64 = 4 waves
    const int wave = threadIdx.x >> 6;
    const int lane = threadIdx.x & 63;
    if (lane == 0) sdata[wave] = v;
    __syncthreads();
    if (threadIdx.x == 0) {
        float t = sdata[0] + sdata[1] + sdata[2] + sdata[3];
        atomicAdd(out, t);
    }
}

extern "C" void kernel_launch(void* const* d_in, const int* in_sizes, int n_in,
                              void* d_out, int out_size, void* d_ws, size_t ws_size,
                              hipStream_t stream) {
    const float* ev    = (const float*)d_in[0];  // event_features [S,H,E,1]
    const int*   mask  = (const int*)  d_in[1];  // event_mask     [S,H,E]
    const float* gr    = (const float*)d_in[2];  // grid_features  [S,H,G,1]
    const float* w     = (const float*)d_in[3];  // weights        [H,1]
    const float* bases = (const float*)d_in[4];  // bases          [H]
    const float* eff   = (const float*)d_in[5];  // effects        [H,1]
    float* out = (float*)d_out;

    // d_out is poisoned 0xAA before every timed launch — zero it (capture-legal).
    hipMemsetAsync(out, 0, sizeof(float), stream);

    // grid=2048 x block=256: nthreads=524288, so Part 1 is exactly 3 iters/thread.
    logic_model_kernel<<<2048, 256, 0, stream>>>(ev, mask, gr, w, bases, eff, out);
}

// Round 3
// 273.219 us; speedup vs baseline: 1.0409x; 1.0108x over previous
//
#include <hip/hip_runtime.h>

// Problem constants (from reference): S=4096, H=3, E=512, G=3334, F=1
constexpr int S = 4096;
constexpr int H = 3;
constexpr int E = 512;
constexpr int G = 3334;
constexpr float RES = 0.03f;             // INTEGRAL_RESOLUTION

constexpr int NBLK = 2048;
constexpr int NTHR = NBLK * 256;         // 524,288
constexpr int NF4E = S * H * E / 4;      // 1,572,864 = exactly 3*NTHR
constexpr int NF4G = S * H * G / 4;      // 10,242,048
constexpr int SLOTS = 20;                // ceil(NF4G / NTHR); only slot 19 partial
constexpr int LAST_VALID = NF4G - (SLOTS - 1) * NTHR;  // 280,576 threads have slot 19

// Sum of exp over one float4 at float4-index fidx. One magic-div per quad;
// row boundary inside the quad handled by compare (G=3334 not /4).
__device__ __forceinline__ float quad_exp(int fidx, float4 y,
                                          float b0, float b1, float b2,
                                          float w0, float w1, float w2) {
    int j = fidx * 4;                    // flat element index into [S*H*G]
    int q = j / G;                       // row  (compiler magic-mul)
    int r = j - q * G;                   // col of elem 0
    int m = q - (q / 3) * 3;             // q % 3 = head of elem 0
    int hB = (m == 2) ? 0 : (m + 1);     // head if elem crosses into next row
    float bbA = (m == 0) ? b0 : ((m == 1) ? b1 : b2);
    float wwA = (m == 0) ? w0 : ((m == 1) ? w1 : w2);
    float bbB = (hB == 0) ? b0 : ((hB == 1) ? b1 : b2);
    float wwB = (hB == 0) ? w0 : ((hB == 1) ? w1 : w2);
    int lim = G - r;                     // elems c >= lim are in row q+1
    float s;
    s  = __expf(bbA + wwA * y.x);        // c=0 never crosses (lim >= 1)
    s += __expf(((1 >= lim) ? bbB : bbA) + ((1 >= lim) ? wwB : wwA) * y.y);
    s += __expf(((2 >= lim) ? bbB : bbA) + ((2 >= lim) ? wwB : wwA) * y.z);
    s += __expf(((3 >= lim) ? bbB : bbA) + ((3 >= lim) ? wwB : wwA) * y.w);
    return s;
}

__global__ __launch_bounds__(256) void logic_model_kernel(
    const float* __restrict__ ev,     // [S*H*E] event_features (F=1)
    const int*   __restrict__ mask,   // [S*H*E] event_mask (0/1)
    const float* __restrict__ gr,     // [S*H*G] grid_features (F=1)
    const float* __restrict__ w,      // [H] weights
    const float* __restrict__ bases,  // [H]
    const float* __restrict__ eff,    // [H] effects
    float* __restrict__ out)
{
    const float b0 = bases[0], b1 = bases[1], b2 = bases[2];
    const float w0 = w[0] * eff[0], w1 = w[1] * eff[1], w2 = w[2] * eff[2];

    const int tid = blockIdx.x * blockDim.x + threadIdx.x;

    const float4* ev4 = (const float4*)ev;
    const int4*   m4  = (const int4*)mask;
    const float4* gr4 = (const float4*)gr;

    // ---- Issue Part-1 loads (6 x 16B) and Part-2 batch 0 (4 x 16B) up front
    float4 x0 = ev4[tid], x1 = ev4[tid + NTHR], x2 = ev4[tid + 2 * NTHR];
    int4   a0 = m4[tid],  a1 = m4[tid + NTHR],  a2 = m4[tid + 2 * NTHR];

    float4 cur[4];
    #pragma unroll
    for (int u = 0; u < 4; ++u) cur[u] = gr4[tid + u * NTHR];

    // ---- Part 1 compute: masked event log-sum (loads already in flight) ----
    float acc_ev = 0.f;
    #pragma unroll
    for (int k = 0; k < 3; ++k) {
        int i = tid + k * NTHR;
        float4 x = (k == 0) ? x0 : ((k == 1) ? x1 : x2);
        int4   m = (k == 0) ? a0 : ((k == 1) ? a1 : a2);
        int row = i >> 7;                // E/4 = 128 float4 per (s,h) row
        int h = row - (row / 3) * 3;
        float bb = (h == 0) ? b0 : ((h == 1) ? b1 : b2);
        float ww = (h == 0) ? w0 : ((h == 1) ? w1 : w2);
        if (m.x) acc_ev += bb + ww * x.x;
        if (m.y) acc_ev += bb + ww * x.y;
        if (m.z) acc_ev += bb + ww * x.z;
        if (m.w) acc_ev += bb + ww * x.w;
    }

    // ---- Part 2: software-pipelined exp-sum, 5 batches of 4 float4 ----
    // Next batch's loads are issued BEFORE the current batch is consumed, so
    // each wave keeps ~8 x 16B loads in flight (the scheduler cannot sink
    // them past the uses of the PREVIOUS batch).
    float acc_gr = 0.f;
    #pragma unroll
    for (int b = 1; b < 5; ++b) {
        float4 nxt[4];
        #pragma unroll
        for (int u = 0; u < 4; ++u) {
            int slot = 4 * b + u;
            int idx = tid + slot * NTHR;
            if (slot == SLOTS - 1) idx = min(idx, NF4G - 1);  // clamp; masked below
            nxt[u] = gr4[idx];
        }
        #pragma unroll
        for (int u = 0; u < 4; ++u)
            acc_gr += quad_exp(tid + (4 * (b - 1) + u) * NTHR, cur[u],
                               b0, b1, b2, w0, w1, w2);
        #pragma unroll
        for (int u = 0; u < 4; ++u) cur[u] = nxt[u];
    }
    // final batch (slots 16..19); slot 19 valid only for tid < LAST_VALID
    #pragma unroll
    for (int u = 0; u < 3; ++u)
        acc_gr += quad_exp(tid + (16 + u) * NTHR, cur[u],
                           b0, b1, b2, w0, w1, w2);
    {
        int idx = min(tid + 19 * NTHR, NF4G - 1);
        float t = quad_exp(idx, cur[3], b0, b1, b2, w0, w1, w2);
        acc_gr += (tid < LAST_VALID) ? t : 0.f;
    }

    float v = acc_ev - RES * acc_gr;

    // ---- Block reduction: wave64 shuffle -> LDS -> one atomic per block ----
    #pragma unroll
    for (int off = 32; off > 0; off >>= 1)
        v += __shfl_down(v, off, 64);

    __shared__ float sdata[4];
    const int wave = threadIdx.x >> 6;
    const int lane = threadIdx.x & 63;
    if (lane == 0) sdata[wave] = v;
    __syncthreads();
    if (threadIdx.x == 0) {
        float t = sdata[0] + sdata[1] + sdata[2] + sdata[3];
        atomicAdd(out, t);
    }
}

extern "C" void kernel_launch(void* const* d_in, const int* in_sizes, int n_in,
                              void* d_out, int out_size, void* d_ws, size_t ws_size,
                              hipStream_t stream) {
    const float* ev    = (const float*)d_in[0];  // event_features [S,H,E,1]
    const int*   mask  = (const int*)  d_in[1];  // event_mask     [S,H,E]
    const float* gr    = (const float*)d_in[2];  // grid_features  [S,H,G,1]
    const float* wgt   = (const float*)d_in[3];  // weights        [H,1]
    const float* bases = (const float*)d_in[4];  // bases          [H]
    const float* eff   = (const float*)d_in[5];  // effects        [H,1]
    float* out = (float*)d_out;

    // d_out is poisoned 0xAA before every timed launch — zero it (capture-legal).
    hipMemsetAsync(out, 0, sizeof(float), stream);

    logic_model_kernel<<<NBLK, 256, 0, stream>>>(ev, mask, gr, wgt, bases, eff, out);
}

// Round 4
// 272.013 us; speedup vs baseline: 1.0455x; 1.0044x over previous
//
#include <hip/hip_runtime.h>

// Problem constants (from reference): S=4096, H=3, E=512, G=3334, F=1
constexpr int S = 4096;
constexpr int H = 3;
constexpr int E = 512;
constexpr int G = 3334;
constexpr float RES = 0.03f;             // INTEGRAL_RESOLUTION
constexpr float LOG2E = 1.44269504088896340736f;

constexpr int NBLK = 2048;
constexpr int BT   = 256;                // threads per block
constexpr int NF4G = S * H * G / 4;      // 10,242,048 float4s of grid
constexpr int GPB  = NF4G / NBLK;        // 5001 float4 per block (exact)
constexpr int NF4E = S * H * E / 4;      // 1,572,864 float4s of events
constexpr int EPB  = NF4E / NBLK;        // 768 = 3*256 per block (exact)
// grid slots: u=0..18 always valid (18*256+255=4863 < 5001); u=19 valid iff t<137
constexpr int TAIL_T = GPB - 19 * BT;    // 137

#if __has_builtin(__builtin_amdgcn_exp2f)
#define EXP2(x) __builtin_amdgcn_exp2f(x)
#else
#define EXP2(x) exp2f(x)
#endif

// Sum of exp2 over one float4 at float4-index fidx (flat in [S*H*G]).
// One magic-div chain per quad; in-quad row crossing handled by compare.
// Constants are pre-scaled by log2(e), so exp(b+w*y) == exp2(c+v*y).
__device__ __forceinline__ float quad_exp(int fidx, float4 y,
                                          float c0, float c1, float c2,
                                          float v0, float v1, float v2) {
    int j = fidx * 4;                    // flat element index
    int q = j / G;                       // row (compiler magic-mul)
    int r = j - q * G;                   // col of elem 0
    int m = q - (q / 3) * 3;             // head of elem 0
    int hB = (m == 2) ? 0 : (m + 1);     // head after a row crossing
    float cA = (m == 0) ? c0 : ((m == 1) ? c1 : c2);
    float vA = (m == 0) ? v0 : ((m == 1) ? v1 : v2);
    float cB = (hB == 0) ? c0 : ((hB == 1) ? c1 : c2);
    float vB = (hB == 0) ? v0 : ((hB == 1) ? v1 : v2);
    int lim = G - r;                     // elems c >= lim belong to row q+1
    float s;
    s  = EXP2(cA + vA * y.x);
    s += EXP2(((1 >= lim) ? cB : cA) + ((1 >= lim) ? vB : vA) * y.y);
    s += EXP2(((2 >= lim) ? cB : cA) + ((2 >= lim) ? vB : vA) * y.z);
    s += EXP2(((3 >= lim) ? cB : cA) + ((3 >= lim) ? vB : vA) * y.w);
    return s;
}

__global__ __launch_bounds__(256) void logic_model_kernel(
    const float* __restrict__ ev,     // [S*H*E] event_features
    const int*   __restrict__ mask,   // [S*H*E] event_mask (0/1)
    const float* __restrict__ gr,     // [S*H*G] grid_features
    const float* __restrict__ w,      // [H] weights
    const float* __restrict__ bases,  // [H]
    const float* __restrict__ eff,    // [H] effects
    float* __restrict__ out)
{
    // Unscaled for Part 1 (log-sum), log2e-scaled for Part 2 (exp2).
    const float b0 = bases[0], b1 = bases[1], b2 = bases[2];
    const float w0 = w[0] * eff[0], w1 = w[1] * eff[1], w2 = w[2] * eff[2];
    const float c0 = b0 * LOG2E, c1 = b1 * LOG2E, c2 = b2 * LOG2E;
    const float v0 = w0 * LOG2E, v1 = w1 * LOG2E, v2 = w2 * LOG2E;

    const int t = threadIdx.x;
    const float4* ev4 = (const float4*)ev;
    const int4*   m4  = (const int4*)mask;
    const float4* gr4 = (const float4*)gr;

    const int ebase = blockIdx.x * EPB + t;   // block-contiguous event chunk
    const int gbase = blockIdx.x * GPB;       // block-contiguous grid chunk

    // ---- Phase A: issue Part-1 loads (6) + grid groups 0..2 (12) ----------
    float4 p1x[3]; int4 p1m[3];
    #pragma unroll
    for (int u = 0; u < 3; ++u) {
        p1x[u] = ev4[ebase + u * BT];
        p1m[u] = m4[ebase + u * BT];
    }
    float4 buf[4][4];                         // 4-group rotation (16 float4)
    #pragma unroll
    for (int g = 0; g < 3; ++g) {
        #pragma unroll
        for (int u = 0; u < 4; ++u) {
            int slot = 4 * g + u;
            buf[g][u] = gr4[gbase + t + slot * BT];   // slots 0..11 always valid
        }
    }
    __builtin_amdgcn_sched_barrier(0);        // loads stay issued HERE

    // ---- Part 1 compute (its loads complete first in vmcnt order) --------
    float acc_ev = 0.f;
    #pragma unroll
    for (int u = 0; u < 3; ++u) {
        int row = (ebase + u * BT) >> 7;      // 128 float4 per (s,h) event row
        int h = row - (row / 3) * 3;
        float bb = (h == 0) ? b0 : ((h == 1) ? b1 : b2);
        float ww = (h == 0) ? w0 : ((h == 1) ? w1 : w2);
        float4 x = p1x[u]; int4 m = p1m[u];
        if (m.x) acc_ev += bb + ww * x.x;
        if (m.y) acc_ev += bb + ww * x.y;
        if (m.z) acc_ev += bb + ww * x.z;
        if (m.w) acc_ev += bb + ww * x.w;
    }
    __builtin_amdgcn_sched_barrier(0);

    // ---- Part 2: rolling pipeline, prefetch distance 3 groups (12 loads) --
    float acc_gr = 0.f;
    #pragma unroll
    for (int b = 0; b < 5; ++b) {
        if (b + 3 < 5) {                      // issue group b+3
            int g = b + 3;
            #pragma unroll
            for (int u = 0; u < 4; ++u) {
                int slot = 4 * g + u;
                int pos = t + slot * BT;
                int idx = gbase + ((slot == 19 && t >= TAIL_T) ? 0 : pos);
                buf[g & 3][u] = gr4[idx];
            }
        }
        __builtin_amdgcn_sched_barrier(0);
        #pragma unroll
        for (int u = 0; u < 4; ++u) {         // consume group b
            int slot = 4 * b + u;
            int pos = t + slot * BT;
            bool valid = (slot < 19) || (t < TAIL_T);
            int fidx = gbase + (valid ? pos : 0);
            float s = quad_exp(fidx, buf[b & 3][u], c0, c1, c2, v0, v1, v2);
            acc_gr += valid ? s : 0.f;
        }
        __builtin_amdgcn_sched_barrier(0);
    }

    float v = acc_ev - RES * acc_gr;

    // ---- Block reduction: wave64 shuffle -> LDS -> one atomic per block ---
    #pragma unroll
    for (int off = 32; off > 0; off >>= 1)
        v += __shfl_down(v, off, 64);

    __shared__ float sdata[4];
    const int wave = threadIdx.x >> 6;
    const int lane = threadIdx.x & 63;
    if (lane == 0) sdata[wave] = v;
    __syncthreads();
    if (threadIdx.x == 0) {
        float s = sdata[0] + sdata[1] + sdata[2] + sdata[3];
        atomicAdd(out, s);
    }
}

extern "C" void kernel_launch(void* const* d_in, const int* in_sizes, int n_in,
                              void* d_out, int out_size, void* d_ws, size_t ws_size,
                              hipStream_t stream) {
    const float* ev    = (const float*)d_in[0];  // event_features [S,H,E,1]
    const int*   mask  = (const int*)  d_in[1];  // event_mask     [S,H,E]
    const float* gr    = (const float*)d_in[2];  // grid_features  [S,H,G,1]
    const float* wgt   = (const float*)d_in[3];  // weights        [H,1]
    const float* bases = (const float*)d_in[4];  // bases          [H]
    const float* eff   = (const float*)d_in[5];  // effects        [H,1]
    float* out = (float*)d_out;

    // d_out is poisoned 0xAA before every timed launch — zero it (capture-legal).
    hipMemsetAsync(out, 0, sizeof(float), stream);

    logic_model_kernel<<<NBLK, BT, 0, stream>>>(ev, mask, gr, wgt, bases, eff, out);
}